// Round 9
// baseline (496.808 us; speedup 1.0000x reference)
//
#include <hip/hip_runtime.h>
#include <hip/hip_bf16.h>
#include <math.h>

#define SS 2048
#define HH 1024
#define NHH 16
#define HDD 64
#define BH 32
#define MM 4096

typedef unsigned short u16;
using bf16x8 = __attribute__((ext_vector_type(8))) short;
using floatx4 = __attribute__((ext_vector_type(4))) float;

__device__ __forceinline__ u16 f2bf(float f) {
  unsigned u = __float_as_uint(f);
  u += 0x7fffu + ((u >> 16) & 1u);
  return (u16)(u >> 16);
}
__device__ __forceinline__ unsigned pk_bf16(float a, float b) {
  union { __hip_bfloat162 h2; unsigned u; } c;
  c.h2 = __float22bfloat162_rn(float2{a, b});
  return c.u;
}
__device__ __forceinline__ void gload_lds16(const u16* g, u16* l) {
  __builtin_amdgcn_global_load_lds(
      (const __attribute__((address_space(1))) void*)g,
      (__attribute__((address_space(3))) void*)l, 16, 0, 0);
}

// ---------------------------------------------------------------------------
// fp32 -> bf16 conversion (hs + 4 weights) + RoPE cos/sin table.
// ---------------------------------------------------------------------------
__global__ __launch_bounds__(256) void convert_bf(
    const float* __restrict__ hs, const float* __restrict__ wq,
    const float* __restrict__ wk, const float* __restrict__ wv,
    const float* __restrict__ wo, const int* __restrict__ pos,
    u16* __restrict__ hs_b, u16* __restrict__ wq_b, u16* __restrict__ wk_b,
    u16* __restrict__ wv_b, u16* __restrict__ wo_b,
    float2* __restrict__ tab) {
  int g = blockIdx.x * 256 + threadIdx.x;
  if (g < 2097152) {
    const float* src;
    u16* dst;
    int off;
    if (g < 1048576) {
      src = hs; dst = hs_b; off = g;
    } else {
      int t = g - 1048576;
      int w = t >> 18;
      off = t & 262143;
      src = (w == 0) ? wq : (w == 1) ? wk : (w == 2) ? wv : wo;
      dst = (w == 0) ? wq_b : (w == 1) ? wk_b : (w == 2) ? wv_b : wo_b;
    }
    float4 v = ((const float4*)src)[off];
    ushort4 o = make_ushort4(f2bf(v.x), f2bf(v.y), f2bf(v.z), f2bf(v.w));
    ((ushort4*)dst)[off] = o;
  } else {
    int idx = g - 2097152;  // 0..65535
    int s = idx >> 5, j = idx & 31;
    float p = (float)pos[s];
    const float c0 = 13.287712379549449f / 32.0f;  // log2(10000)/32
    float f = p * exp2f(-(float)j * c0);
    float sn, cs;
    sincosf(f, &sn, &cs);
    tab[idx] = float2{cs, sn};
  }
}

// ---------------------------------------------------------------------------
// QKV MFMA GEMM: 128x128 tile, BK=32, global_load_lds w16, XOR swizzle.
// grid.x spans Wq|Wk|Wv; Q/K get table RoPE in the epilogue (Q pre-scaled by
// (1/sqrt(HD))*log2e), bf16 head-major out; V written transposed Vt[bh][d][s].
// ---------------------------------------------------------------------------
__global__ __launch_bounds__(256) void mfma_gemm_qkv(
    const u16* __restrict__ X, const u16* __restrict__ W0,
    const u16* __restrict__ W1, const u16* __restrict__ W2,
    const float* __restrict__ b0, const float* __restrict__ b1,
    const float* __restrict__ b2, const float2* __restrict__ tab,
    u16* __restrict__ O0, u16* __restrict__ O1, u16* __restrict__ O2) {
  __shared__ __align__(16) u16 As[128 * 32];
  __shared__ __align__(16) u16 Bs[128 * 32];
  const int tid = threadIdx.x;
  const int lane = tid & 63;
  const int wvu = __builtin_amdgcn_readfirstlane(tid >> 6);
  const int l15 = lane & 15;
  const int quad = lane >> 4;
  const int wm = wvu >> 1, wn = wvu & 1;
  const int m0 = blockIdx.y * 128;
  const int n0g = blockIdx.x * 128;
  const int lr = lane >> 2;
  const int lc = lane & 3;

  int wsel = n0g >> 10;
  int n0 = n0g & 1023;
  const u16* Wsel = (wsel == 1) ? W1 : (wsel == 2) ? W2 : W0;
  const float* bsel = (wsel == 1) ? b1 : (wsel == 2) ? b2 : b0;
  u16* Osel = (wsel == 1) ? O1 : (wsel == 2) ? O2 : O0;

  floatx4 acc[4][4];
#pragma unroll
  for (int i = 0; i < 4; ++i)
#pragma unroll
    for (int j = 0; j < 4; ++j) acc[i][j] = (floatx4){0.f, 0.f, 0.f, 0.f};

  const int scol = (lc ^ ((lr >> 1) & 3)) * 8;
  const int fsw = ((l15 >> 1) & 3);

  for (int k0 = 0; k0 < HH; k0 += 32) {
#pragma unroll
    for (int u = 0; u < 2; ++u) {
      int r = u * 64 + wvu * 16 + lr;
      gload_lds16(&X[(size_t)(m0 + r) * HH + k0 + scol],
                  &As[(u * 64 + wvu * 16) * 32]);
      gload_lds16(&Wsel[(size_t)(n0 + r) * HH + k0 + scol],
                  &Bs[(u * 64 + wvu * 16) * 32]);
    }
    __syncthreads();
    bf16x8 af[4], bfr[4];
#pragma unroll
    for (int mb = 0; mb < 4; ++mb)
      af[mb] = *(const bf16x8*)&As[(wm * 64 + mb * 16 + l15) * 32 +
                                   ((quad ^ fsw) * 8)];
#pragma unroll
    for (int nb = 0; nb < 4; ++nb)
      bfr[nb] = *(const bf16x8*)&Bs[(wn * 64 + nb * 16 + l15) * 32 +
                                    ((quad ^ fsw) * 8)];
#pragma unroll
    for (int mb = 0; mb < 4; ++mb)
#pragma unroll
      for (int nb = 0; nb < 4; ++nb)
        acc[mb][nb] = __builtin_amdgcn_mfma_f32_16x16x32_bf16(
            af[mb], bfr[nb], acc[mb][nb], 0, 0, 0);
    __syncthreads();
  }

  if (wsel < 2) {
    const float qs = (wsel == 0) ? 0.125f * 1.44269504088896f : 1.0f;
    const int colb = n0 + wn * 64;
    const int h = colb >> 6;
    const float bias0 = bsel[colb + l15];
    const float bias1 = bsel[colb + 16 + l15];
    const float bias2 = bsel[colb + 32 + l15];
    const float bias3 = bsel[colb + 48 + l15];
#pragma unroll
    for (int mb = 0; mb < 4; ++mb)
#pragma unroll
      for (int r = 0; r < 4; ++r) {
        int m = m0 + wm * 64 + mb * 16 + quad * 4 + r;
        int b = m >> 11, s = m & (SS - 1);
        float2 t0 = tab[s * 32 + l15];
        float2 t1 = tab[s * 32 + 16 + l15];
        size_t obase = ((size_t)(b * NHH + h) * SS + s) * HDD;
        float x1 = acc[mb][0][r] + bias0;
        float x2 = acc[mb][2][r] + bias2;
        Osel[obase + l15] = f2bf((x1 * t0.x - x2 * t0.y) * qs);
        Osel[obase + 32 + l15] = f2bf((x2 * t0.x + x1 * t0.y) * qs);
        float y1 = acc[mb][1][r] + bias1;
        float y2 = acc[mb][3][r] + bias3;
        Osel[obase + 16 + l15] = f2bf((y1 * t1.x - y2 * t1.y) * qs);
        Osel[obase + 48 + l15] = f2bf((y2 * t1.x + y1 * t1.y) * qs);
      }
  } else {
#pragma unroll
    for (int nb = 0; nb < 4; ++nb) {
      int col = n0 + wn * 64 + nb * 16 + l15;
      int h = col >> 6, d = col & 63;
      float bias = bsel[col];
#pragma unroll
      for (int mb = 0; mb < 4; ++mb) {
        int m = m0 + wm * 64 + mb * 16 + quad * 4;
        int b = m >> 11, s = m & (SS - 1);
        uint2 w2;
        w2.x = pk_bf16(acc[mb][nb][0] + bias, acc[mb][nb][1] + bias);
        w2.y = pk_bf16(acc[mb][nb][2] + bias, acc[mb][nb][3] + bias);
        *(uint2*)&Osel[((size_t)((b * NHH + h) * HDD + d)) * SS + s] = w2;
      }
    }
  }
}

// ---------------------------------------------------------------------------
// Final projection GEMM: 128(m) x 64(n) tiles -> 512 blocks. fp32 out.
// ---------------------------------------------------------------------------
__global__ __launch_bounds__(256) void gemm_out(const u16* __restrict__ X,
                                                const u16* __restrict__ W,
                                                float* __restrict__ Ofp) {
  __shared__ __align__(16) u16 As[128 * 32];
  __shared__ __align__(16) u16 Bs[64 * 32];
  const int tid = threadIdx.x;
  const int lane = tid & 63;
  const int wvu = __builtin_amdgcn_readfirstlane(tid >> 6);
  const int l15 = lane & 15;
  const int quad = lane >> 4;
  const int wm = wvu >> 1, wn = wvu & 1;
  const int m0 = blockIdx.y * 128;
  const int n0 = blockIdx.x * 64;
  const int lr = lane >> 2;
  const int lc = lane & 3;

  floatx4 acc[4][2];
#pragma unroll
  for (int i = 0; i < 4; ++i)
#pragma unroll
    for (int j = 0; j < 2; ++j) acc[i][j] = (floatx4){0.f, 0.f, 0.f, 0.f};

  const int scol = (lc ^ ((lr >> 1) & 3)) * 8;
  const int fsw = ((l15 >> 1) & 3);

  for (int k0 = 0; k0 < HH; k0 += 32) {
#pragma unroll
    for (int u = 0; u < 2; ++u) {
      int r = u * 64 + wvu * 16 + lr;
      gload_lds16(&X[(size_t)(m0 + r) * HH + k0 + scol],
                  &As[(u * 64 + wvu * 16) * 32]);
    }
    gload_lds16(&W[(size_t)(n0 + wvu * 16 + lr) * HH + k0 + scol],
                &Bs[(wvu * 16) * 32]);
    __syncthreads();
    bf16x8 af[4], bfr[2];
#pragma unroll
    for (int mb = 0; mb < 4; ++mb)
      af[mb] = *(const bf16x8*)&As[(wm * 64 + mb * 16 + l15) * 32 +
                                   ((quad ^ fsw) * 8)];
#pragma unroll
    for (int nb = 0; nb < 2; ++nb)
      bfr[nb] = *(const bf16x8*)&Bs[(wn * 32 + nb * 16 + l15) * 32 +
                                    ((quad ^ fsw) * 8)];
#pragma unroll
    for (int mb = 0; mb < 4; ++mb)
#pragma unroll
      for (int nb = 0; nb < 2; ++nb)
        acc[mb][nb] = __builtin_amdgcn_mfma_f32_16x16x32_bf16(
            af[mb], bfr[nb], acc[mb][nb], 0, 0, 0);
    __syncthreads();
  }

#pragma unroll
  for (int mb = 0; mb < 4; ++mb)
#pragma unroll
    for (int r = 0; r < 4; ++r) {
      int m = m0 + wm * 64 + mb * 16 + quad * 4 + r;
#pragma unroll
      for (int nb = 0; nb < 2; ++nb)
        Ofp[(size_t)m * HH + n0 + wn * 32 + nb * 16 + l15] = acc[mb][nb][r];
    }
}

// ---------------------------------------------------------------------------
// Flash attention v3: ALL-REGISTER K-loop, 32-qrow blocks, grid 2048 (8/CU
// available vs 4 before -- grid size was the occupancy cap, rounds 5-8).
// Wave (kh,qh) owns keys kh*32..+31 x qrows qh*16..+15. Q, K AND V frags all
// load directly global->register: the permuted-PV A-operand is two 8B chunks
// per d-row that live in one 64B line (keys kh*32..+31 = full line). No LDS,
// no waitcnt coupling, zero bank conflicts in the loop; compiler pipelines
// loads via register vmcnt. 1-tile manual software pipeline. qh-duplicate
// K/V reads served by L1 (same CU, same lines). LDS only for the epilogue
// kh-half combine. bh on blockIdx.x keeps per-XCD K/V L2-resident.
// ---------------------------------------------------------------------------
__global__ __launch_bounds__(256, 4) void attn_mfma(const u16* __restrict__ Qg,
                                                    const u16* __restrict__ Kg,
                                                    const u16* __restrict__ Vtg,
                                                    u16* __restrict__ A) {
  __shared__ float sred[64 + 2 * 16 * 68];  // lpart[4][16] + Opart[2][16][68]
  const int tid = threadIdx.x;
  const int lane = tid & 63;
  const int wv = __builtin_amdgcn_readfirstlane(tid >> 6);
  const int l15 = lane & 15, quad = lane >> 4;
  const int bh = blockIdx.x, qt = blockIdx.y;  // qt in [0,64): 32 qrows
  const size_t hb = (size_t)bh * SS * HDD;     // Q,K [bh][s][d]; Vt [bh][d][s]
  const int kh = wv >> 1, qh = wv & 1;

  // Q B-frags (loop-invariant): qrows qt*32 + qh*16 + l15
  const u16* qptr = Qg + hb + (size_t)(qt * 32 + qh * 16 + l15) * HDD + quad * 8;
  bf16x8 qf0 = *(const bf16x8*)qptr;
  bf16x8 qf1 = *(const bf16x8*)(qptr + 32);

  // K A-frag base: row kh*32 + kmb*16 + l15, chunk quad*8
  const u16* kbase = Kg + hb + (size_t)(kh * 32 + l15) * HDD + quad * 8;
  // V A-frag base (permuted layout): d-row l15 (+dmb*16), keys kh*32+quad*4
  const u16* vbase = Vtg + hb + (size_t)l15 * SS + kh * 32 + quad * 4;

  // preload tile 0
  bf16x8 kf[2][2];
#pragma unroll
  for (int kmb = 0; kmb < 2; ++kmb)
#pragma unroll
    for (int ch = 0; ch < 2; ++ch)
      kf[kmb][ch] = *(const bf16x8*)&kbase[(size_t)(kmb * 16) * HDD + ch * 32];
  uint2 vlo[4], vhi[4];
#pragma unroll
  for (int dmb = 0; dmb < 4; ++dmb) {
    const u16* vr = vbase + (size_t)(dmb * 16) * SS;
    vlo[dmb] = *(const uint2*)vr;
    vhi[dmb] = *(const uint2*)(vr + 16);
  }

  float l_acc = 0.f;
  floatx4 o[4];
#pragma unroll
  for (int dmb = 0; dmb < 4; ++dmb) o[dmb] = (floatx4){0.f, 0.f, 0.f, 0.f};

  for (int t = 0; t < SS / 64; ++t) {
    // prefetch t+1 (registers only; compiler inserts fine-grained vmcnt)
    const int tn = (t + 1 < SS / 64) ? t + 1 : t;
    bf16x8 kn[2][2];
#pragma unroll
    for (int kmb = 0; kmb < 2; ++kmb)
#pragma unroll
      for (int ch = 0; ch < 2; ++ch)
        kn[kmb][ch] =
            *(const bf16x8*)&kbase[(size_t)(tn * 64 + kmb * 16) * HDD + ch * 32];
    uint2 vnlo[4], vnhi[4];
#pragma unroll
    for (int dmb = 0; dmb < 4; ++dmb) {
      const u16* vr = vbase + (size_t)(dmb * 16) * SS + tn * 64;
      vnlo[dmb] = *(const uint2*)vr;
      vnhi[dmb] = *(const uint2*)(vr + 16);
    }

    // S^T quadrant: key = kmb*16 + quad*4 + r, qrow = l15
    floatx4 st[2];
#pragma unroll
    for (int kmb = 0; kmb < 2; ++kmb) {
      floatx4 z = (floatx4){0.f, 0.f, 0.f, 0.f};
      z = __builtin_amdgcn_mfma_f32_16x16x32_bf16(kf[kmb][0], qf0, z, 0, 0, 0);
      z = __builtin_amdgcn_mfma_f32_16x16x32_bf16(kf[kmb][1], qf1, z, 0, 0, 0);
      st[kmb] = z;
    }

    // exp2 + pack P into permuted MFMA-B layout (in-register)
    float p00 = exp2f(st[0][0]), p01 = exp2f(st[0][1]);
    float p02 = exp2f(st[0][2]), p03 = exp2f(st[0][3]);
    float p10 = exp2f(st[1][0]), p11 = exp2f(st[1][1]);
    float p12 = exp2f(st[1][2]), p13 = exp2f(st[1][3]);
    l_acc += ((p00 + p01) + (p02 + p03)) + ((p10 + p11) + (p12 + p13));
    union { bf16x8 v; unsigned u[4]; } pu;
    pu.u[0] = pk_bf16(p00, p01);
    pu.u[1] = pk_bf16(p02, p03);
    pu.u[2] = pk_bf16(p10, p11);
    pu.u[3] = pk_bf16(p12, p13);

    // O^T += V^T(perm) · P(perm)
#pragma unroll
    for (int dmb = 0; dmb < 4; ++dmb) {
      union { bf16x8 v; uint2 d2[2]; } au;
      au.d2[0] = vlo[dmb];
      au.d2[1] = vhi[dmb];
      o[dmb] =
          __builtin_amdgcn_mfma_f32_16x16x32_bf16(au.v, pu.v, o[dmb], 0, 0, 0);
    }

    // rotate
#pragma unroll
    for (int kmb = 0; kmb < 2; ++kmb)
#pragma unroll
      for (int ch = 0; ch < 2; ++ch) kf[kmb][ch] = kn[kmb][ch];
#pragma unroll
    for (int dmb = 0; dmb < 4; ++dmb) {
      vlo[dmb] = vnlo[dmb];
      vhi[dmb] = vnhi[dmb];
    }
  }

  // ---- epilogue: combine key-halves via LDS (only barriers in kernel) ----
  float* const lpart = sred;        // [4][16]
  float* const Opart = sred + 64;   // [2][16][68]

  l_acc += __shfl_xor(l_acc, 16);
  l_acc += __shfl_xor(l_acc, 32);
  __syncthreads();  // harmless ordering point before LDS writes
  if (quad == 0) lpart[wv * 16 + l15] = l_acc;
  if (kh == 1) {
    float* dst = Opart + qh * (16 * 68);
#pragma unroll
    for (int dmb = 0; dmb < 4; ++dmb)
      *(floatx4*)&dst[l15 * 68 + dmb * 16 + quad * 4] = o[dmb];
  }
  __syncthreads();
  if (kh == 0) {
    const int b = bh >> 4, h = bh & 15;
    const float* src = Opart + qh * (16 * 68);
    const float inv =
        1.f / (lpart[qh * 16 + l15] + lpart[(qh + 2) * 16 + l15]);
    const int s = qt * 32 + qh * 16 + l15;
#pragma unroll
    for (int dmb = 0; dmb < 4; ++dmb) {
      floatx4 part = *(const floatx4*)&src[l15 * 68 + dmb * 16 + quad * 4];
      floatx4 tot = (o[dmb] + part) * inv;
      uint2 w2;
      w2.x = pk_bf16(tot[0], tot[1]);
      w2.y = pk_bf16(tot[2], tot[3]);
      *(uint2*)&A[((size_t)(b * SS + s) * HH) + h * HDD + dmb * 16 +
                  quad * 4] = w2;
    }
  }
}

// ---------------------------------------------------------------------------
extern "C" void kernel_launch(void* const* d_in, const int* in_sizes, int n_in,
                              void* d_out, int out_size, void* d_ws,
                              size_t ws_size, hipStream_t stream) {
  const float* hs = (const float*)d_in[0];
  const int* pos = (const int*)d_in[1];
  const float* Wq = (const float*)d_in[2];
  const float* bq = (const float*)d_in[3];
  const float* Wk = (const float*)d_in[4];
  const float* bk = (const float*)d_in[5];
  const float* Wv = (const float*)d_in[6];
  const float* bv = (const float*)d_in[7];
  const float* Wo = (const float*)d_in[8];
  float* out = (float*)d_out;

  u16* hs_b = (u16*)d_ws;      // 4M
  u16* wq_b = hs_b + 4194304;  // 1M each
  u16* wk_b = wq_b + 1048576;
  u16* wv_b = wk_b + 1048576;
  u16* wo_b = wv_b + 1048576;
  u16* Qb = wo_b + 1048576;    // 4M each
  u16* Kb = Qb + 4194304;
  u16* Vtb = Kb + 4194304;     // transposed V [bh][d][s]
  u16* Ab = Vtb + 4194304;
  float2* tab = (float2*)(Ab + 4194304);  // [2048][32] cos/sin

  hipLaunchKernelGGL(convert_bf, dim3(8448), dim3(256), 0, stream, hs, Wq, Wk,
                     Wv, Wo, pos, hs_b, wq_b, wk_b, wv_b, wo_b, tab);
  hipLaunchKernelGGL(mfma_gemm_qkv, dim3(24, 32), dim3(256), 0, stream, hs_b,
                     wq_b, wk_b, wv_b, bq, bk, bv, tab, Qb, Kb, Vtb);
  hipLaunchKernelGGL(attn_mfma, dim3(32, 64), dim3(256), 0, stream, Qb, Kb,
                     Vtb, Ab);
  hipLaunchKernelGGL(gemm_out, dim3(16, 32), dim3(256), 0, stream, Ab, wo_b,
                     out);
}